// Round 1
// baseline (1839.910 us; speedup 1.0000x reference)
//
#include <hip/hip_runtime.h>
#include <math.h>

#define PSZ 256
#define NPATCH 127
#define L 16129            // 127*127
#define KTOP 4
#define NSEG 16
#define SEGLEN 1009        // ceil(L/NSEG); 16*1009 = 16144 >= 16129
#define MSTRIDE 1012       // pad to multiple of 4 for aligned float4 LDS reads
#define TMAIN 256
#define RPT 8              // rows per thread in main kernel
#define ROWS_PER_BLOCK (TMAIN * RPT)   // 2048
#define NROWBLK 8                      // 8*2048 = 16384 >= L
#define ROWPAD 16384

// ---- workspace layout (float elements) ----
static constexpr size_t OFF_CMAX = 0;                         // [2][256][256]
static constexpr size_t OFF_CMIN = OFF_CMAX + 2 * PSZ * PSZ;
static constexpr size_t OFF_REFG = OFF_CMIN + 2 * PSZ * PSZ;
static constexpr size_t OFF_XG   = OFF_REFG + 2 * PSZ * PSZ;
static constexpr size_t OFF_IP   = OFF_XG   + 2 * PSZ * PSZ;  // [2][9][L] input patches
static constexpr size_t OFF_RP   = OFF_IP   + 2 * 9 * L;      // [2][9][L] ref patches
static constexpr size_t OFF_NI   = OFF_RP   + 2 * 9 * L;      // [2][L]
static constexpr size_t OFF_NR   = OFF_NI   + 2 * L;          // [2][L]
static constexpr size_t OFF_MUI  = OFF_NR   + 2 * L;          // [2][9]
static constexpr size_t OFF_MUR  = OFF_MUI  + 18;             // [2][9]
static constexpr size_t OFF_A    = OFF_MUR  + 18;             // [2][L][9]  input_norm (row-major)
static constexpr size_t OFF_B    = OFF_A    + 2 * L * 9;      // [2][9][L]  ref_norm (p-major)
static constexpr size_t OFF_PV   = OFF_B    + 2 * 9 * L;      // [2][NSEG][ROWPAD][4] partial vals
static constexpr size_t OFF_PI   = OFF_PV   + 2 * NSEG * ROWPAD * 4; // same, int idx
static constexpr size_t OFF_IDX  = OFF_PI   + 2 * NSEG * ROWPAD * 4; // [2][L][4] final idx (int)

__device__ __forceinline__ void ins4(float val, int m,
    float& v0, float& v1, float& v2, float& v3,
    int& i0, int& i1, int& i2, int& i3) {
  // strict > everywhere: equal values keep the earlier (smaller-m) entry first,
  // matching jax.lax.top_k tie-break when candidates arrive in ascending m.
  if (val > v3) {
    if (val > v2) {
      v3 = v2; i3 = i2;
      if (val > v1) {
        v2 = v1; i2 = i1;
        if (val > v0) { v1 = v0; i1 = i0; v0 = val; i0 = m; }
        else          { v1 = val; i1 = m; }
      } else { v2 = val; i2 = m; }
    } else { v3 = val; i3 = m; }
  }
}

// k1: per pixel: channel max/min of x, channel mean of ref, copy x -> out[:, :3]
__global__ void k1_pixel(const float* __restrict__ x, const float* __restrict__ ref,
                         float* __restrict__ ws, float* __restrict__ out) {
  int id = blockIdx.x * 256 + threadIdx.x;
  if (id >= 2 * PSZ * PSZ) return;
  int b = id >> 16;
  int pix = id & 0xFFFF;
  const float* xb = x + (size_t)b * 3 * PSZ * PSZ + pix;
  float c0 = xb[0], c1 = xb[PSZ * PSZ], c2 = xb[2 * PSZ * PSZ];
  ws[OFF_CMAX + id] = fmaxf(fmaxf(c0, c1), c2);
  ws[OFF_CMIN + id] = fminf(fminf(c0, c1), c2);
  const float* rb = ref + (size_t)b * 3 * PSZ * PSZ + pix;
  ws[OFF_REFG + id] = (rb[0] + rb[PSZ * PSZ] + rb[2 * PSZ * PSZ]) / 3.0f;
  float* ob = out + (size_t)b * 7 * PSZ * PSZ + pix;
  ob[0] = c0; ob[PSZ * PSZ] = c1; ob[2 * PSZ * PSZ] = c2;
}

// k2: x_gray = 3x3 clipped-window max of cmax - cmin
__global__ void k2_gray(float* __restrict__ ws) {
  int id = blockIdx.x * 256 + threadIdx.x;
  if (id >= 2 * PSZ * PSZ) return;
  int b = id >> 16;
  int pix = id & 0xFFFF;
  int y = pix >> 8, xx = pix & 255;
  const float* cm = ws + OFF_CMAX + ((size_t)b << 16);
  float m = -3.402823466e+38f;
  for (int dy = -1; dy <= 1; ++dy) {
    int yy = y + dy;
    if (yy < 0 || yy > 255) continue;
    for (int dx = -1; dx <= 1; ++dx) {
      int xc = xx + dx;
      if (xc < 0 || xc > 255) continue;
      m = fmaxf(m, cm[yy * PSZ + xc]);
    }
  }
  ws[OFF_XG + id] = m - ws[OFF_CMIN + id];
}

// k3: unfold patches (p = 3*di + dj), plus per-patch norms (uncentered, f32 like reference)
__global__ void k3_patch(float* __restrict__ ws) {
  int id = blockIdx.x * 256 + threadIdx.x;
  if (id >= 2 * L) return;
  int b = id / L, m = id % L;
  int i = m / NPATCH, j = m % NPATCH;
  const float* xg = ws + OFF_XG + ((size_t)b << 16);
  const float* rg = ws + OFF_REFG + ((size_t)b << 16);
  float si = 0.f, sr = 0.f;
  for (int di = 0; di < 3; ++di) {
    for (int dj = 0; dj < 3; ++dj) {
      int p = di * 3 + dj;
      float vi = xg[(2 * i + di) * PSZ + 2 * j + dj];
      float vr = rg[(2 * i + di) * PSZ + 2 * j + dj];
      ws[OFF_IP + ((size_t)b * 9 + p) * L + m] = vi;
      ws[OFF_RP + ((size_t)b * 9 + p) * L + m] = vr;
      si += vi * vi;
      sr += vr * vr;
    }
  }
  ws[OFF_NI + id] = sqrtf(si);
  ws[OFF_NR + id] = sqrtf(sr);
}

// k4: per-(b,p) mean over L in f64 (deterministic tree reduction)
__global__ void k4_mean(float* __restrict__ ws) {
  __shared__ double sm[256];
  int which = blockIdx.x / 18;  // 0 = ip, 1 = rp
  int bp = blockIdx.x % 18;
  const float* src = ws + (which ? OFF_RP : OFF_IP) + (size_t)bp * L;
  double s = 0.0;
  for (int l = threadIdx.x; l < L; l += 256) s += (double)src[l];
  sm[threadIdx.x] = s;
  __syncthreads();
  for (int st = 128; st > 0; st >>= 1) {
    if ((int)threadIdx.x < st) sm[threadIdx.x] += sm[threadIdx.x + st];
    __syncthreads();
  }
  if (threadIdx.x == 0)
    ws[(which ? OFF_MUR : OFF_MUI) + bp] = (float)(sm[0] / (double)L);
}

// k5: build normalized matrices. A[b][l][9] = (ip - muI)/nI ; B[b][9][L] = (rp - muR)/nR
__global__ void k5_norm(float* __restrict__ ws) {
  int id = blockIdx.x * 256 + threadIdx.x;
  if (id >= 2 * L) return;
  int b = id / L, l = id % L;
  float ni = ws[OFF_NI + id], nr = ws[OFF_NR + id];
  for (int p = 0; p < 9; ++p) {
    float mi = ws[OFF_MUI + b * 9 + p];
    float mr = ws[OFF_MUR + b * 9 + p];
    float vi = ws[OFF_IP + ((size_t)b * 9 + p) * L + l];
    float vr = ws[OFF_RP + ((size_t)b * 9 + p) * L + l];
    ws[OFF_A + ((size_t)b * L + l) * 9 + p] = (vi - mi) / ni;
    ws[OFF_B + ((size_t)b * 9 + p) * L + l] = (vr - mr) / nr;
  }
}

// k6: fused ncc + per-segment top-4.
// grid: 2(b) x 8(rowblk) x 16(seg) = 256 blocks, 256 threads, 8 rows/thread, 4 m/iter.
__global__ __launch_bounds__(TMAIN, 2) void k6_topk(float* __restrict__ ws) {
  __shared__ float lds[9 * MSTRIDE];  // 36432 B
  int bid = blockIdx.x;
  int seg = bid & 15;
  int rowblk = (bid >> 4) & 7;
  int b = bid >> 7;
  int m0 = seg * SEGLEN;
  int mend = m0 + SEGLEN;
  if (mend > L) mend = L;
  int mlen = mend - m0;

  const float* Bg = ws + OFF_B + (size_t)b * 9 * L + m0;
  for (int p = 0; p < 9; ++p)
    for (int mm = threadIdx.x; mm < mlen; mm += TMAIN)
      lds[p * MSTRIDE + mm] = Bg[(size_t)p * L + mm];
  __syncthreads();

  int row0 = rowblk * ROWS_PER_BLOCK + threadIdx.x * RPT;
  float a[RPT][9];
#pragma unroll
  for (int r = 0; r < RPT; ++r) {
    int row = row0 + r;
    if (row > L - 1) row = L - 1;
    const float* Ap = ws + OFF_A + ((size_t)b * L + row) * 9;
#pragma unroll
    for (int p = 0; p < 9; ++p) a[r][p] = Ap[p];
  }

  float tv[RPT][4];
  int ti[RPT][4];
#pragma unroll
  for (int r = 0; r < RPT; ++r) {
#pragma unroll
    for (int q = 0; q < 4; ++q) { tv[r][q] = -3.402823466e+38f; ti[r][q] = 0; }
  }

  int mlen4 = mlen & ~3;
  for (int mm = 0; mm < mlen4; mm += 4) {
    float s[RPT][4];
    {
      const float4 bq = *reinterpret_cast<const float4*>(&lds[mm]);
#pragma unroll
      for (int r = 0; r < RPT; ++r) {
        s[r][0] = a[r][0] * bq.x;
        s[r][1] = a[r][0] * bq.y;
        s[r][2] = a[r][0] * bq.z;
        s[r][3] = a[r][0] * bq.w;
      }
    }
#pragma unroll
    for (int p = 1; p < 9; ++p) {
      const float4 bq = *reinterpret_cast<const float4*>(&lds[p * MSTRIDE + mm]);
#pragma unroll
      for (int r = 0; r < RPT; ++r) {
        s[r][0] = fmaf(a[r][p], bq.x, s[r][0]);
        s[r][1] = fmaf(a[r][p], bq.y, s[r][1]);
        s[r][2] = fmaf(a[r][p], bq.z, s[r][2]);
        s[r][3] = fmaf(a[r][p], bq.w, s[r][3]);
      }
    }
#pragma unroll
    for (int r = 0; r < RPT; ++r) {
      float rm = fmaxf(fmaxf(s[r][0], s[r][1]), fmaxf(s[r][2], s[r][3]));
      if (rm > tv[r][3]) {
        ins4(s[r][0], m0 + mm + 0, tv[r][0], tv[r][1], tv[r][2], tv[r][3], ti[r][0], ti[r][1], ti[r][2], ti[r][3]);
        ins4(s[r][1], m0 + mm + 1, tv[r][0], tv[r][1], tv[r][2], tv[r][3], ti[r][0], ti[r][1], ti[r][2], ti[r][3]);
        ins4(s[r][2], m0 + mm + 2, tv[r][0], tv[r][1], tv[r][2], tv[r][3], ti[r][0], ti[r][1], ti[r][2], ti[r][3]);
        ins4(s[r][3], m0 + mm + 3, tv[r][0], tv[r][1], tv[r][2], tv[r][3], ti[r][0], ti[r][1], ti[r][2], ti[r][3]);
      }
    }
  }
  // tail (ascending m preserves tie semantics)
  for (int mm = mlen4; mm < mlen; ++mm) {
    float bb[9];
#pragma unroll
    for (int p = 0; p < 9; ++p) bb[p] = lds[p * MSTRIDE + mm];
#pragma unroll
    for (int r = 0; r < RPT; ++r) {
      float sv = a[r][0] * bb[0];
#pragma unroll
      for (int p = 1; p < 9; ++p) sv = fmaf(a[r][p], bb[p], sv);
      if (sv > tv[r][3])
        ins4(sv, m0 + mm, tv[r][0], tv[r][1], tv[r][2], tv[r][3], ti[r][0], ti[r][1], ti[r][2], ti[r][3]);
    }
  }

  int* wsi = (int*)ws;
#pragma unroll
  for (int r = 0; r < RPT; ++r) {
    int row = row0 + r;
    if (row < L) {
      size_t base = (((size_t)b * NSEG + seg) * ROWPAD + row) * 4;
#pragma unroll
      for (int q = 0; q < 4; ++q) {
        ws[OFF_PV + base + q] = tv[r][q];
        wsi[OFF_PI + base + q] = ti[r][q];
      }
    }
  }
}

// k7: merge per-segment top-4 (segments ascending -> tie-break = lower m first)
__global__ void k7_merge(float* __restrict__ ws) {
  int id = blockIdx.x * 256 + threadIdx.x;
  if (id >= 2 * L) return;
  int b = id / L, row = id % L;
  float v0 = -3.402823466e+38f, v1 = v0, v2 = v0, v3 = v0;
  int i0 = 0, i1 = 0, i2 = 0, i3 = 0;
  const int* wsi_c = (const int*)ws;
  for (int s = 0; s < NSEG; ++s) {
    size_t base = (((size_t)b * NSEG + s) * ROWPAD + row) * 4;
    for (int q = 0; q < 4; ++q) {
      float val = ws[OFF_PV + base + q];
      int m = wsi_c[OFF_PI + base + q];
      ins4(val, m, v0, v1, v2, v3, i0, i1, i2, i3);
    }
  }
  int* wsi = (int*)ws;
  size_t ib = OFF_IDX + (size_t)id * 4;
  wsi[ib] = i0; wsi[ib + 1] = i1; wsi[ib + 2] = i2; wsi[ib + 3] = i3;
}

// k8: fold (overlap-add) via per-output-pixel gather; di/dj ascending matches reference add order
__global__ void k8_fold(const float* __restrict__ ws, float* __restrict__ out) {
  int id = blockIdx.x * 256 + threadIdx.x;
  if (id >= 2 * KTOP * PSZ * PSZ) return;
  int b = id / (KTOP * PSZ * PSZ);
  int rem = id % (KTOP * PSZ * PSZ);
  int kk = rem >> 16;
  int pix = rem & 0xFFFF;
  int y = pix >> 8, xx = pix & 255;
  const int* wsi = (const int*)ws;
  float acc = 0.f;
  for (int di = 0; di < 3; ++di) {
    int yy = y - di;
    if (yy < 0 || (yy & 1) || (yy >> 1) >= NPATCH) continue;
    int i = yy >> 1;
    for (int dj = 0; dj < 3; ++dj) {
      int xc = xx - dj;
      if (xc < 0 || (xc & 1) || (xc >> 1) >= NPATCH) continue;
      int j = xc >> 1;
      int l = i * NPATCH + j;
      int m = wsi[OFF_IDX + ((size_t)b * L + l) * 4 + kk];
      acc += ws[OFF_RP + ((size_t)b * 9 + di * 3 + dj) * L + m];
    }
  }
  out[(((size_t)b * 7 + 3 + kk) * PSZ + y) * PSZ + xx] = acc;
}

extern "C" void kernel_launch(void* const* d_in, const int* in_sizes, int n_in,
                              void* d_out, int out_size, void* d_ws, size_t ws_size,
                              hipStream_t stream) {
  const float* x = (const float*)d_in[0];
  const float* ref = (const float*)d_in[1];
  float* ws = (float*)d_ws;
  float* out = (float*)d_out;

  k1_pixel<<<512, 256, 0, stream>>>(x, ref, ws, out);
  k2_gray<<<512, 256, 0, stream>>>(ws);
  k3_patch<<<(2 * L + 255) / 256, 256, 0, stream>>>(ws);
  k4_mean<<<36, 256, 0, stream>>>(ws);
  k5_norm<<<(2 * L + 255) / 256, 256, 0, stream>>>(ws);
  k6_topk<<<2 * NROWBLK * NSEG, TMAIN, 0, stream>>>(ws);
  k7_merge<<<(2 * L + 255) / 256, 256, 0, stream>>>(ws);
  k8_fold<<<(2 * KTOP * PSZ * PSZ + 255) / 256, 256, 0, stream>>>(ws, out);
}